// Round 3
// baseline (1779.445 us; speedup 1.0000x reference)
//
#include <hip/hip_runtime.h>
#include <stdint.h>
#include <math.h>

typedef unsigned short u16;
typedef __attribute__((ext_vector_type(8))) short short8;
typedef __attribute__((ext_vector_type(4))) float floatx4;

#define SEQ    4096
#define NBATCH 2
#define DMODEL 768
#define NHEADS 12
#define DHEAD  64
#define FFDIM  3072
#define BHS    (NBATCH*NHEADS*SEQ*DHEAD)   // 6291456 elems per head-major tensor

static __device__ __forceinline__ float b2f(u16 u) {
    union { float f; unsigned int i; } x; x.i = ((unsigned int)u) << 16; return x.f;
}
static __device__ __forceinline__ u16 f2b(float f) {
    union { float f; unsigned int i; } x; x.f = f;
    unsigned int r = x.i + 0x7fffu + ((x.i >> 16) & 1u);
    return (u16)(r >> 16);
}
// flag-aware load: f==1 -> bf16 array, f==0 -> f32 array
static __device__ __forceinline__ float ldany(const void* p, size_t i, int f) {
    return f ? b2f(((const u16*)p)[i]) : ((const float*)p)[i];
}

// dtype probe: emb_ln_g is all-ones. bf16 pair = 0x3F803F80, f32 one = 0x3F800000.
__global__ void detect_kernel(const void* g1, int* dtf) {
    dtf[0] = (((const unsigned int*)g1)[0] == 0x3F803F80u) ? 1 : 0;
}

// ---------------------------------------------------------------------------
// bf16 MFMA GEMM: C[M,N] = A[M,K] @ Bt[N,K]^T (+bias)
// EPI 0: scatter to 3 head-major bufs (scale tensor 0 by 0.125)
// EPI 1: outf[idx] += acc + bias      (in-place residual add, f32)
// EPI 2: out_bf16 = gelu(acc + bias)
// ---------------------------------------------------------------------------
template<int EPI>
__global__ __launch_bounds__(256, 2) void gemm128(
    const u16* __restrict__ A, const u16* __restrict__ Bt,
    const u16* __restrict__ bias,
    float* __restrict__ outf, u16* __restrict__ outb,
    int M, int N, int K)
{
    const int tid  = threadIdx.x;
    const int wave = tid >> 6, lane = tid & 63;
    const int l15 = lane & 15, l4 = lane >> 4;
    const int mb = blockIdx.y * 128, nb = blockIdx.x * 128;
    const int wr = (wave >> 1) * 64, wc = (wave & 1) * 64;

    __shared__ __align__(16) u16 As[128 * 64];
    __shared__ __align__(16) u16 Bs[128 * 64];

    const floatx4 fzero = {0.f, 0.f, 0.f, 0.f};
    floatx4 acc[4][4];
#pragma unroll
    for (int i = 0; i < 4; ++i)
#pragma unroll
        for (int j = 0; j < 4; ++j) acc[i][j] = fzero;

    for (int k0 = 0; k0 < K; k0 += 64) {
        __syncthreads();
#pragma unroll
        for (int p = 0; p < 4; ++p) {
            int ch = p * 256 + tid, row = ch >> 3, sl = ch & 7;
            int sw = (sl ^ (row & 7)) << 3;
            short8 va = *reinterpret_cast<const short8*>(A + (size_t)(mb + row) * K + k0 + sl * 8);
            *reinterpret_cast<short8*>(&As[row * 64 + sw]) = va;
            short8 vb = *reinterpret_cast<const short8*>(Bt + (size_t)(nb + row) * K + k0 + sl * 8);
            *reinterpret_cast<short8*>(&Bs[row * 64 + sw]) = vb;
        }
        __syncthreads();

        short8 af[4][2], bfr[4][2];
#pragma unroll
        for (int mi = 0; mi < 4; ++mi)
#pragma unroll
            for (int ks = 0; ks < 2; ++ks) {
                int row = wr + mi * 16 + l15;
                af[mi][ks] = *reinterpret_cast<const short8*>(
                    &As[row * 64 + (((ks * 4 + l4) ^ (row & 7)) << 3)]);
            }
#pragma unroll
        for (int ni = 0; ni < 4; ++ni)
#pragma unroll
            for (int ks = 0; ks < 2; ++ks) {
                int row = wc + ni * 16 + l15;
                bfr[ni][ks] = *reinterpret_cast<const short8*>(
                    &Bs[row * 64 + (((ks * 4 + l4) ^ (row & 7)) << 3)]);
            }
#pragma unroll
        for (int ks = 0; ks < 2; ++ks)
#pragma unroll
            for (int mi = 0; mi < 4; ++mi)
#pragma unroll
                for (int ni = 0; ni < 4; ++ni)
                    acc[mi][ni] = __builtin_amdgcn_mfma_f32_16x16x32_bf16(
                        af[mi][ks], bfr[ni][ks], acc[mi][ni], 0, 0, 0);
    }

#pragma unroll
    for (int mi = 0; mi < 4; ++mi)
#pragma unroll
        for (int ni = 0; ni < 4; ++ni) {
            int gcol = nb + wc + ni * 16 + l15;
            float bvl = b2f(bias[gcol]);
#pragma unroll
            for (int r = 0; r < 4; ++r) {
                int grow = mb + wr + mi * 16 + l4 * 4 + r;
                float v = acc[mi][ni][r] + bvl;
                if constexpr (EPI == 0) {
                    int tsel = gcol / DMODEL;           // 0,1,2
                    int hd = gcol % DMODEL;
                    int hh = hd >> 6, dd = hd & 63;
                    int bb = grow >> 12, ss = grow & (SEQ - 1);
                    float scl = (tsel == 0) ? 0.125f : 1.0f;
                    outb[(size_t)tsel * BHS +
                         (((size_t)(bb * NHEADS + hh)) * SEQ + ss) * DHEAD + dd] = f2b(v * scl);
                } else if constexpr (EPI == 1) {
                    size_t idx = (size_t)grow * N + gcol;
                    outf[idx] = v + outf[idx];
                } else {
                    float gl = 0.5f * v * (1.f + erff(v * 0.70710678118654752f));
                    outb[(size_t)grow * N + gcol] = f2b(gl);
                }
            }
        }
}

// ---------------------------------------------------------------------------
// Flash-style attention. GLOB=false: band+global-key attention per (chunk,h,b).
// GLOB=true: global-query attention per (h,b), writes rows < G only.
// ---------------------------------------------------------------------------
template<bool GLOB>
__global__ __launch_bounds__(256, 2) void attn_kernel(
    const u16* __restrict__ q, const u16* __restrict__ k, const u16* __restrict__ v,
    const int* __restrict__ mask, const int* __restrict__ nglob,
    u16* __restrict__ out)
{
    const int tid = threadIdx.x, wave = tid >> 6, lane = tid & 63;
    const int l15 = lane & 15, l4 = lane >> 4;
    const int c = blockIdx.x;
    const int hh = blockIdx.y, b = blockIdx.z;
    const int G = nglob[0];
    const size_t ho = (size_t)(b * NHEADS + hh) * SEQ * DHEAD;
    const int qbase = GLOB ? 0 : c * 128;

    __shared__ __align__(16) u16 Qs[128 * 64];
    __shared__ __align__(16) u16 Ks[64 * 64];
    __shared__ __align__(16) u16 Vt[64 * 64];
    __shared__ __align__(16) u16 Ps[4][32 * 64];

#pragma unroll
    for (int p = 0; p < 4; ++p) {
        int ch = p * 256 + tid, row = ch >> 3, sl = ch & 7;
        short8 vv = *reinterpret_cast<const short8*>(q + ho + (size_t)(qbase + row) * DHEAD + sl * 8);
        *reinterpret_cast<short8*>(&Qs[row * 64 + ((sl ^ (row & 7)) << 3)]) = vv;
    }

    const floatx4 fzero = {0.f, 0.f, 0.f, 0.f};
    floatx4 o[2][4];
    float m_[2][4], l_[2][4];
#pragma unroll
    for (int mi = 0; mi < 2; ++mi)
#pragma unroll
        for (int r = 0; r < 4; ++r) { m_[mi][r] = -INFINITY; l_[mi][r] = 0.f; }
#pragma unroll
    for (int mi = 0; mi < 2; ++mi)
#pragma unroll
        for (int ni = 0; ni < 4; ++ni) o[mi][ni] = fzero;

    const int NT = GLOB ? (SEQ / 64) : 8;
    for (int t = 0; t < NT; ++t) {
        __syncthreads();
        const bool isg = (!GLOB) && (t < 2);
        const int base = GLOB ? t * 64 : (isg ? t * 64 : (c * 128 - 128 + (t - 2) * 64));

#pragma unroll
        for (int p = 0; p < 2; ++p) {
            int ch = p * 256 + tid, row = ch >> 3, sl = ch & 7;
            int kr = base + row;
            int krc = kr < 0 ? 0 : (kr > SEQ - 1 ? SEQ - 1 : kr);
            short8 kv = *reinterpret_cast<const short8*>(k + ho + (size_t)krc * DHEAD + sl * 8);
            *reinterpret_cast<short8*>(&Ks[row * 64 + ((sl ^ (row & 7)) << 3)]) = kv;
            short8 vv = *reinterpret_cast<const short8*>(v + ho + (size_t)krc * DHEAD + sl * 8);
#pragma unroll
            for (int i = 0; i < 8; ++i) {
                int d = sl * 8 + i;
                Vt[d * 64 + (((row >> 3) ^ (d & 7)) << 3) + (row & 7)] = (u16)vv[i];
            }
        }
        __syncthreads();

        floatx4 sc[2][4];
#pragma unroll
        for (int mi = 0; mi < 2; ++mi)
#pragma unroll
            for (int ni = 0; ni < 4; ++ni) sc[mi][ni] = fzero;
#pragma unroll
        for (int ks = 0; ks < 2; ++ks) {
            short8 af[2], bfr[4];
#pragma unroll
            for (int mi = 0; mi < 2; ++mi) {
                int row = wave * 32 + mi * 16 + l15;
                af[mi] = *reinterpret_cast<const short8*>(
                    &Qs[row * 64 + (((ks * 4 + l4) ^ (row & 7)) << 3)]);
            }
#pragma unroll
            for (int ni = 0; ni < 4; ++ni) {
                int row = ni * 16 + l15;
                bfr[ni] = *reinterpret_cast<const short8*>(
                    &Ks[row * 64 + (((ks * 4 + l4) ^ (row & 7)) << 3)]);
            }
#pragma unroll
            for (int mi = 0; mi < 2; ++mi)
#pragma unroll
                for (int ni = 0; ni < 4; ++ni)
                    sc[mi][ni] = __builtin_amdgcn_mfma_f32_16x16x32_bf16(
                        af[mi], bfr[ni], sc[mi][ni], 0, 0, 0);
        }

#pragma unroll
        for (int ni = 0; ni < 4; ++ni) {
            int col = ni * 16 + l15;
            int kabs = base + col;
            if (GLOB) {
                bool okc = mask[b * SEQ + kabs] > 0;
                if (!okc) {
#pragma unroll
                    for (int mi = 0; mi < 2; ++mi)
#pragma unroll
                        for (int r = 0; r < 4; ++r) sc[mi][ni][r] = -1e9f;
                }
            } else if (isg) {
                bool okc = (t * 64 + col) < G;
                if (!okc) {
#pragma unroll
                    for (int mi = 0; mi < 2; ++mi)
#pragma unroll
                        for (int r = 0; r < 4; ++r) sc[mi][ni][r] = -1e9f;
                }
            } else {
                int kc = kabs < 0 ? 0 : (kabs > SEQ - 1 ? SEQ - 1 : kabs);
                bool okc = (kabs >= 0) && (kabs < SEQ) && (kabs >= G) && (mask[b * SEQ + kc] > 0);
#pragma unroll
                for (int mi = 0; mi < 2; ++mi)
#pragma unroll
                    for (int r = 0; r < 4; ++r) {
                        int qrow = wave * 32 + mi * 16 + l4 * 4 + r;
                        int rel = kabs - (qbase + qrow);
                        bool ok = okc && (rel >= -128) && (rel <= 128);
                        if (!ok) sc[mi][ni][r] = -1e9f;
                    }
            }
        }

#pragma unroll
        for (int mi = 0; mi < 2; ++mi)
#pragma unroll
            for (int r = 0; r < 4; ++r) {
                float mx = fmaxf(fmaxf(sc[mi][0][r], sc[mi][1][r]),
                                 fmaxf(sc[mi][2][r], sc[mi][3][r]));
#pragma unroll
                for (int d = 1; d < 16; d <<= 1) mx = fmaxf(mx, __shfl_xor(mx, d, 64));
                float nm = fmaxf(m_[mi][r], mx);
                float al = __expf(m_[mi][r] - nm);
                float ss = 0.f;
#pragma unroll
                for (int ni = 0; ni < 4; ++ni) {
                    float p = __expf(sc[mi][ni][r] - nm);
                    sc[mi][ni][r] = p; ss += p;
                }
#pragma unroll
                for (int d = 1; d < 16; d <<= 1) ss += __shfl_xor(ss, d, 64);
                l_[mi][r] = l_[mi][r] * al + ss;
                m_[mi][r] = nm;
#pragma unroll
                for (int ni = 0; ni < 4; ++ni) o[mi][ni][r] *= al;
            }

#pragma unroll
        for (int mi = 0; mi < 2; ++mi)
#pragma unroll
            for (int ni = 0; ni < 4; ++ni)
#pragma unroll
                for (int r = 0; r < 4; ++r) {
                    int prow = mi * 16 + l4 * 4 + r, pcol = ni * 16 + l15;
                    Ps[wave][prow * 64 + (((pcol >> 3) ^ (prow & 7)) << 3) + (pcol & 7)] =
                        f2b(sc[mi][ni][r]);
                }

#pragma unroll
        for (int ks = 0; ks < 2; ++ks) {
            short8 pa[2];
#pragma unroll
            for (int mi = 0; mi < 2; ++mi) {
                int row = mi * 16 + l15;
                pa[mi] = *reinterpret_cast<const short8*>(
                    &Ps[wave][row * 64 + (((ks * 4 + l4) ^ (row & 7)) << 3)]);
            }
#pragma unroll
            for (int ni = 0; ni < 4; ++ni) {
                int row = ni * 16 + l15;
                short8 vb = *reinterpret_cast<const short8*>(
                    &Vt[row * 64 + (((ks * 4 + l4) ^ (row & 7)) << 3)]);
#pragma unroll
                for (int mi = 0; mi < 2; ++mi)
                    o[mi][ni] = __builtin_amdgcn_mfma_f32_16x16x32_bf16(pa[mi], vb, o[mi][ni], 0, 0, 0);
            }
        }
    }

#pragma unroll
    for (int mi = 0; mi < 2; ++mi)
#pragma unroll
        for (int r = 0; r < 4; ++r) {
            int qrow = wave * 32 + mi * 16 + l4 * 4 + r;
            if (GLOB && qrow >= G) continue;
            float inv = 1.f / l_[mi][r];
            int s = qbase + qrow;
#pragma unroll
            for (int ni = 0; ni < 4; ++ni)
                out[((size_t)(b * SEQ + s)) * DMODEL + hh * DHEAD + ni * 16 + l15] =
                    f2b(o[mi][ni][r] * inv);
        }
}

// ---------------------------------------------------------------------------
__global__ __launch_bounds__(256) void ln_kernel(
    const float* __restrict__ in, const void* __restrict__ g, const void* __restrict__ be,
    size_t eoff, float* __restrict__ hout, u16* __restrict__ hbf,
    const int* __restrict__ dtf)
{
    int f = dtf[0];
    int row = blockIdx.x;
    const float* xr = in + (size_t)row * DMODEL;
    float v0[3]; float s = 0.f, qq = 0.f;
#pragma unroll
    for (int i = 0; i < 3; ++i) {
        float t = xr[threadIdx.x + i * 256]; v0[i] = t; s += t; qq += t * t;
    }
#pragma unroll
    for (int d = 1; d < 64; d <<= 1) { s += __shfl_xor(s, d, 64); qq += __shfl_xor(qq, d, 64); }
    __shared__ float red[8];
    int wv = threadIdx.x >> 6;
    if ((threadIdx.x & 63) == 0) { red[wv] = s; red[4 + wv] = qq; }
    __syncthreads();
    s = red[0] + red[1] + red[2] + red[3];
    qq = red[4] + red[5] + red[6] + red[7];
    float mean = s * (1.f / DMODEL);
    float var = qq * (1.f / DMODEL) - mean * mean;
    float inv = rsqrtf(var + 1e-5f);
#pragma unroll
    for (int i = 0; i < 3; ++i) {
        int d = threadIdx.x + i * 256;
        float y = (v0[i] - mean) * inv * ldany(g, eoff + d, f) + ldany(be, eoff + d, f);
        hout[(size_t)row * DMODEL + d] = y;
        hbf[(size_t)row * DMODEL + d] = f2b(y);
    }
}

__global__ __launch_bounds__(256) void embed_kernel(
    const int* __restrict__ x, const void* __restrict__ ew, const void* __restrict__ ep,
    const void* __restrict__ g, const void* __restrict__ be,
    float* __restrict__ hout, u16* __restrict__ hbf, const int* __restrict__ dtf)
{
    int f = dtf[0];
    int row = blockIdx.x;
    int spos = row & (SEQ - 1);
    int tok = x[row];
    float v0[3]; float s = 0.f, qq = 0.f;
#pragma unroll
    for (int i = 0; i < 3; ++i) {
        int d = threadIdx.x + i * 256;
        float t = ldany(ew, (size_t)tok * DMODEL + d, f) + ldany(ep, (size_t)spos * DMODEL + d, f);
        v0[i] = t; s += t; qq += t * t;
    }
#pragma unroll
    for (int d = 1; d < 64; d <<= 1) { s += __shfl_xor(s, d, 64); qq += __shfl_xor(qq, d, 64); }
    __shared__ float red[8];
    int wv = threadIdx.x >> 6;
    if ((threadIdx.x & 63) == 0) { red[wv] = s; red[4 + wv] = qq; }
    __syncthreads();
    s = red[0] + red[1] + red[2] + red[3];
    qq = red[4] + red[5] + red[6] + red[7];
    float mean = s * (1.f / DMODEL);
    float var = qq * (1.f / DMODEL) - mean * mean;
    float inv = rsqrtf(var + 1e-5f);
#pragma unroll
    for (int i = 0; i < 3; ++i) {
        int d = threadIdx.x + i * 256;
        float y = (v0[i] - mean) * inv * ldany(g, d, f) + ldany(be, d, f);
        hout[(size_t)row * DMODEL + d] = y;
        hbf[(size_t)row * DMODEL + d] = f2b(y);
    }
}

// out[n][k] = bf16(in[eoff + k*N + n]); block (32,8), grid (N/32, K/32)
__global__ void transpose_off(const void* __restrict__ in, size_t eoff,
                              u16* __restrict__ out, int K, int N,
                              const int* __restrict__ dtf)
{
    int f = dtf[0];
    __shared__ u16 tl[32][33];
    int n0 = blockIdx.x * 32, k0 = blockIdx.y * 32;
    for (int i = threadIdx.y; i < 32; i += 8)
        tl[i][threadIdx.x] = f2b(ldany(in, eoff + (size_t)(k0 + i) * N + n0 + threadIdx.x, f));
    __syncthreads();
    for (int i = threadIdx.y; i < 32; i += 8)
        out[(size_t)(n0 + i) * K + k0 + threadIdx.x] = tl[threadIdx.x][i];
}

// convert up to 3 bias vectors (n_each elems each, shared element offset)
__global__ void cvt3_off(const void* s0, const void* s1, const void* s2, size_t eoff,
                         u16* dst, int n_each, const int* __restrict__ dtf)
{
    int f = dtf[0];
    int i = blockIdx.x * 256 + threadIdx.x;
    if (i >= 3 * n_each) return;
    int t = i / n_each, j = i % n_each;
    const void* src = t == 0 ? s0 : t == 1 ? s1 : s2;
    if (!src) return;
    dst[i] = f2b(ldany(src, eoff + j, f));
}

// classifier head; writes d_out as bf16 or f32 per flag
__global__ __launch_bounds__(256) void cls_kernel(
    const float* __restrict__ h,
    const void* __restrict__ W1c, const void* __restrict__ b1c,
    const void* __restrict__ W2c, const void* __restrict__ b2c,
    void* __restrict__ outp, const int* __restrict__ dtf)
{
    int f = dtf[0];
    __shared__ float h0[DMODEL], h1[DMODEL];
    __shared__ float y1[2][DMODEL];
    __shared__ float red[4];
    for (int d = threadIdx.x; d < DMODEL; d += 256) {
        h0[d] = h[d];
        h1[d] = h[(size_t)SEQ * DMODEL + d];
    }
    __syncthreads();
    for (int n = threadIdx.x; n < DMODEL; n += 256) {
        float a0 = ldany(b1c, n, f), a1 = a0;
        for (int kk = 0; kk < DMODEL; ++kk) {
            float wv = ldany(W1c, (size_t)kk * DMODEL + n, f);
            a0 += h0[kk] * wv; a1 += h1[kk] * wv;
        }
        y1[0][n] = 0.5f * a0 * (1.f + erff(a0 * 0.70710678118654752f));
        y1[1][n] = 0.5f * a1 * (1.f + erff(a1 * 0.70710678118654752f));
    }
    __syncthreads();
    for (int bb = 0; bb < 2; ++bb) {
        float p = 0.f;
        for (int n = threadIdx.x; n < DMODEL; n += 256) p += y1[bb][n] * ldany(W2c, n, f);
#pragma unroll
        for (int d = 1; d < 64; d <<= 1) p += __shfl_xor(p, d, 64);
        if ((threadIdx.x & 63) == 0) red[threadIdx.x >> 6] = p;
        __syncthreads();
        if (threadIdx.x == 0) {
            float r = red[0] + red[1] + red[2] + red[3] + ldany(b2c, 0, f);
            if (f) ((u16*)outp)[bb] = f2b(r);
            else   ((float*)outp)[bb] = r;
        }
        __syncthreads();
    }
}

// ---------------------------------------------------------------------------
extern "C" void kernel_launch(void* const* d_in, const int* in_sizes, int n_in,
                              void* d_out, int out_size, void* d_ws, size_t ws_size,
                              hipStream_t stream)
{
    (void)in_sizes; (void)n_in; (void)out_size; (void)ws_size;
    const int* x     = (const int*)d_in[0];
    const int* mask  = (const int*)d_in[1];
    const int* nglob = (const int*)d_in[3];
    const void* emb_word = d_in[4];
    const void* emb_pos  = d_in[5];
    const void* eg  = d_in[6];
    const void* eb  = d_in[7];
    const void* Wq  = d_in[8];  const void* bq  = d_in[9];
    const void* Wk  = d_in[10]; const void* bk  = d_in[11];
    const void* Wv  = d_in[12]; const void* bv  = d_in[13];
    const void* Wqg = d_in[14]; const void* bqg = d_in[15];
    const void* Wkg = d_in[16]; const void* bkg = d_in[17];
    const void* Wvg = d_in[18]; const void* bvg = d_in[19];
    const void* Wo  = d_in[20]; const void* bo  = d_in[21];
    const void* ln1g = d_in[22]; const void* ln1b = d_in[23];
    const void* W1  = d_in[24]; const void* b1  = d_in[25];
    const void* W2  = d_in[26]; const void* b2  = d_in[27];
    const void* ln2g = d_in[28]; const void* ln2b = d_in[29];
    const void* cW1 = d_in[30]; const void* cb1 = d_in[31];
    const void* cW2 = d_in[32]; const void* cb2 = d_in[33];

    // workspace layout (total ~88.5 MiB)
    char* w = (char*)d_ws;
    float* h_f  = (float*)(w);                       // 25,165,824
    u16* h_b    = (u16*)(w + 25165824);              // 12,582,912
    u16* qkv3   = (u16*)(w + 37748736);              // 37,748,736 (3 head-major bufs)
    u16* ffn_b  = qkv3;                              // ffn acts use [37748736, 88080384)
    u16* attn_b = (u16*)(w + 75497472);              // 12,582,912 (tail; dead when ffn runs)
    u16* Wt     = (u16*)(w + 88080384);              // 4,718,592 (transposed weights)
    u16* bws    = (u16*)(w + 92798976);              // 6,144 (bf16 biases)
    int* dtf    = (int*)(w + 92805120);              // 4 (dtype flag)

    const int ROWS = NBATCH * SEQ;  // 8192
    dim3 tb(32, 8);

    detect_kernel<<<1, 1, 0, stream>>>(eg, dtf);
    embed_kernel<<<ROWS, 256, 0, stream>>>(x, emb_word, emb_pos, eg, eb, h_f, h_b, dtf);

    for (int l = 0; l < 2; ++l) {
        const size_t wOff  = (size_t)l * DMODEL * DMODEL;
        const size_t bOff  = (size_t)l * DMODEL;
        const size_t w1Off = (size_t)l * DMODEL * FFDIM;
        const size_t f1Off = (size_t)l * FFDIM;

        // ---- band QKV projection + band attention ----
        transpose_off<<<dim3(24, 24), tb, 0, stream>>>(Wq, wOff, Wt + 0 * 589824, DMODEL, DMODEL, dtf);
        transpose_off<<<dim3(24, 24), tb, 0, stream>>>(Wk, wOff, Wt + 1 * 589824, DMODEL, DMODEL, dtf);
        transpose_off<<<dim3(24, 24), tb, 0, stream>>>(Wv, wOff, Wt + 2 * 589824, DMODEL, DMODEL, dtf);
        cvt3_off<<<9, 256, 0, stream>>>(bq, bk, bv, bOff, bws, DMODEL, dtf);
        gemm128<0><<<dim3(18, 64), 256, 0, stream>>>(h_b, Wt, bws, nullptr, qkv3,
                                                     ROWS, 3 * DMODEL, DMODEL);
        attn_kernel<false><<<dim3(32, NHEADS, NBATCH), 256, 0, stream>>>(
            qkv3, qkv3 + BHS, qkv3 + 2 * (size_t)BHS, mask, nglob, attn_b);

        // ---- global QKV projection + global attention (rows < G) ----
        transpose_off<<<dim3(24, 24), tb, 0, stream>>>(Wqg, wOff, Wt + 0 * 589824, DMODEL, DMODEL, dtf);
        transpose_off<<<dim3(24, 24), tb, 0, stream>>>(Wkg, wOff, Wt + 1 * 589824, DMODEL, DMODEL, dtf);
        transpose_off<<<dim3(24, 24), tb, 0, stream>>>(Wvg, wOff, Wt + 2 * 589824, DMODEL, DMODEL, dtf);
        cvt3_off<<<9, 256, 0, stream>>>(bqg, bkg, bvg, bOff, bws, DMODEL, dtf);
        gemm128<0><<<dim3(18, 64), 256, 0, stream>>>(h_b, Wt, bws, nullptr, qkv3,
                                                     ROWS, 3 * DMODEL, DMODEL);
        attn_kernel<true><<<dim3(1, NHEADS, NBATCH), 256, 0, stream>>>(
            qkv3, qkv3 + BHS, qkv3 + 2 * (size_t)BHS, mask, nglob, attn_b);

        // ---- output projection + residual (in-place h_f), LN1 ----
        transpose_off<<<dim3(24, 24), tb, 0, stream>>>(Wo, wOff, Wt, DMODEL, DMODEL, dtf);
        cvt3_off<<<9, 256, 0, stream>>>(bo, nullptr, nullptr, bOff, bws, DMODEL, dtf);
        gemm128<1><<<dim3(6, 64), 256, 0, stream>>>(attn_b, Wt, bws, h_f, nullptr,
                                                    ROWS, DMODEL, DMODEL);
        ln_kernel<<<ROWS, 256, 0, stream>>>(h_f, ln1g, ln1b, bOff, h_f, h_b, dtf);

        // ---- FFN ----
        transpose_off<<<dim3(96, 24), tb, 0, stream>>>(W1, w1Off, Wt, DMODEL, FFDIM, dtf);
        cvt3_off<<<36, 256, 0, stream>>>(b1, nullptr, nullptr, f1Off, bws, FFDIM, dtf);
        gemm128<2><<<dim3(24, 64), 256, 0, stream>>>(h_b, Wt, bws, nullptr, ffn_b,
                                                     ROWS, FFDIM, DMODEL);
        transpose_off<<<dim3(24, 96), tb, 0, stream>>>(W2, w1Off, Wt, FFDIM, DMODEL, dtf);
        cvt3_off<<<9, 256, 0, stream>>>(b2, nullptr, nullptr, bOff, bws, DMODEL, dtf);
        gemm128<1><<<dim3(6, 64), 256, 0, stream>>>(ffn_b, Wt, bws, h_f, nullptr,
                                                    ROWS, DMODEL, FFDIM);
        ln_kernel<<<ROWS, 256, 0, stream>>>(h_f, ln2g, ln2b, bOff, h_f, h_b, dtf);
    }
    cls_kernel<<<1, 256, 0, stream>>>(h_f, cW1, cb1, cW2, cb2, d_out, dtf);
}